// Round 8
// baseline (3510.923 us; speedup 1.0000x reference)
//
#include <hip/hip_runtime.h>
#include <hip/hip_bf16.h>

#define OUT_DIM 4096
#define IN_DIM  4096
#define RANK    64
#define M_DIM   16384   // B*S = 4*4096

typedef short  s16x8 __attribute__((ext_vector_type(8)));
typedef __bf16 b16x8 __attribute__((ext_vector_type(8)));
typedef float  f32x4 __attribute__((ext_vector_type(4)));

// ---- MFMA wrapper: tolerate either builtin signature (short8 or bf16x8) ----
template <typename T>
__device__ static inline auto mfma_sel(T a, T b, f32x4 c, int)
    -> decltype(__builtin_amdgcn_mfma_f32_16x16x32_bf16(a, b, c, 0, 0, 0)) {
  return __builtin_amdgcn_mfma_f32_16x16x32_bf16(a, b, c, 0, 0, 0);
}
template <typename T>
__device__ static inline f32x4 mfma_sel(T a, T b, f32x4 c, long) {
  return __builtin_amdgcn_mfma_f32_16x16x32_bf16(
      __builtin_bit_cast(b16x8, a), __builtin_bit_cast(b16x8, b), c, 0, 0, 0);
}
__device__ static inline f32x4 mfma_bf16(s16x8 a, s16x8 b, f32x4 c) {
  return mfma_sel(a, b, c, 0);
}

// ---- fp32 -> bf16 bits, round-to-nearest-even ----
__device__ static inline unsigned short f2bf(float f) {
  unsigned int u = __float_as_uint(f);
  u += 0x7fffu + ((u >> 16) & 1u);
  return (unsigned short)(u >> 16);
}

// ---- async global->LDS, 16B per lane ----
__device__ static inline void gload16(const unsigned short* g, unsigned short* l) {
  __builtin_amdgcn_global_load_lds(
      (const __attribute__((address_space(1))) void*)g,
      (__attribute__((address_space(3))) void*)l, 16, 0, 0);
}

// ============ kernel 1: sigma gating + scaled factors ============
__global__ void prep_kernel(const float* __restrict__ U_top, const float* __restrict__ S_top,
                            const float* __restrict__ alpha, const float* __restrict__ beta,
                            const float* __restrict__ U_tail, const float* __restrict__ S_tail,
                            float* __restrict__ A1, float* __restrict__ A2) {
  int idx = blockIdx.x * 256 + threadIdx.x;       // over OUT_DIM*RANK
  int r = idx & (RANK - 1);
  float sig = S_top[r] * alpha[r] + beta[r];
  sig = sig > 0.f ? sig : 0.f;
  A1[idx] = U_top[idx] * sig;
  A2[idx] = U_tail[idx] * S_tail[r];
}

// ============ kernel 2: RV = R @ Vh_tail  (64 x IN), 8 r per block ============
__global__ void rv_kernel(const float* __restrict__ Rm, const float* __restrict__ Vh_tail,
                          float* __restrict__ RV) {
  const int i  = blockIdx.x * 256 + threadIdx.x;  // 0..IN_DIM-1
  const int r0 = blockIdx.y * 8;
  float acc[8] = {};
  for (int q = 0; q < RANK; ++q) {
    float v = Vh_tail[(size_t)q * IN_DIM + i];
#pragma unroll
    for (int rr = 0; rr < 8; ++rr)
      acc[rr] = fmaf(Rm[(r0 + rr) * RANK + q], v, acc[rr]);   // uniform -> s_load
  }
#pragma unroll
  for (int rr = 0; rr < 8; ++rr) RV[(size_t)(r0 + rr) * IN_DIM + i] = acc[rr];
}

// ============ kernel 3: x -> bf16 ============
__global__ void cvt_kernel(const float* __restrict__ x, unsigned short* __restrict__ xb) {
  const long long n8 = (long long)M_DIM * IN_DIM / 8;
  long long idx = (long long)blockIdx.x * blockDim.x + threadIdx.x;
  const long long stride = (long long)gridDim.x * blockDim.x;
  for (; idx < n8; idx += stride) {
    const f32x4* p = (const f32x4*)(x + idx * 8);
    f32x4 v0 = p[0], v1 = p[1];
    s16x8 o;
    o[0] = (short)f2bf(v0[0]); o[1] = (short)f2bf(v0[1]);
    o[2] = (short)f2bf(v0[2]); o[3] = (short)f2bf(v0[3]);
    o[4] = (short)f2bf(v1[0]); o[5] = (short)f2bf(v1[1]);
    o[6] = (short)f2bf(v1[2]); o[7] = (short)f2bf(v1[3]);
    *(s16x8*)(xb + idx * 8) = o;
  }
}

// ============ kernel 4: W_tilde (bf16, [OUT][IN] = B^T layout) ============
#define WT_O 16
__global__ void wtilde_kernel(const float* __restrict__ W,  const float* __restrict__ A1,
                              const float* __restrict__ A2, const float* __restrict__ Vh_top,
                              const float* __restrict__ RV, unsigned short* __restrict__ Wb) {
  const int i  = blockIdx.x * 256 + threadIdx.x;
  const int o0 = blockIdx.y * WT_O;
  float acc[WT_O];
#pragma unroll
  for (int o = 0; o < WT_O; ++o) acc[o] = W[(size_t)(o0 + o) * IN_DIM + i];
#pragma unroll 4
  for (int r = 0; r < RANK; ++r) {
    float vt = Vh_top[(size_t)r * IN_DIM + i];
    float rv = RV[(size_t)r * IN_DIM + i];
#pragma unroll
    for (int o = 0; o < WT_O; ++o) {
      acc[o] = fmaf(A1[(o0 + o) * RANK + r], vt, acc[o]);
      acc[o] = fmaf(A2[(o0 + o) * RANK + r], rv, acc[o]);
    }
  }
#pragma unroll
  for (int o = 0; o < WT_O; ++o)
    Wb[(size_t)(o0 + o) * IN_DIM + i] = f2bf(acc[o]);
}

// ============ kernel 5: 256x256 GEMM, 4 waves x (128x128), BK=32 ============
// Fat-wave geometry: 0.25 ds_read per MFMA (vs 0.375 at 128x64) -> LDS-read
// time (1536 cyc/CU/K64) < MFMA time (2483 cyc) even fully serialized.
// 64 KB LDS (2 buf) -> 2 blocks/CU; independent barriers de-skew the blocks
// so one block's ds_reads overlap the other's MFMAs.
// Sync per tile: issue 8 gload16 (t+1 -> buf^1) at top (full-tile cover),
// ds_read 16 frags from buf, 64 MFMA, vmcnt(0), barrier. 1 barrier/tile.
#define BM  256
#define BN  256
#define BK2 32
#define NT2 (IN_DIM / BK2)   // 128

__global__ __launch_bounds__(256, 2) void gemm_kernel(
    const unsigned short* __restrict__ A,   // xb [M][K] bf16 bits
    const unsigned short* __restrict__ Bw,  // Wb [N][K] bf16 bits
    const float* __restrict__ bias,
    float* __restrict__ C) {
  __shared__ unsigned short lds[2][2][BM * BK2];   // 2 x 2 x 16 KB = 64 KB

  const int tid = threadIdx.x;
  const int l   = tid & 63;
  const int wid = tid >> 6;                 // 0..3
  const int wr  = wid >> 1;                 // 0..1  (M split)
  const int wc  = wid & 1;                  // 0..1  (N split)

  // XCD swizzle: 1024 blocks, 8 XCDs, nwg%8==0 -> simple bijection.
  const int bid = blockIdx.x;
  const int swz = (bid & 7) * 128 + (bid >> 3);
  const int nt_ = swz >> 6;                 // 0..15
  const int mt_ = swz & 63;                 // 0..63
  const long long tileM = (long long)mt_ * BM;
  const long long tileN = (long long)nt_ * BN;

  // ---- staging geometry (linear LDS dest, inverse-swizzled global src) ----
  // 64B rows (BK=32): 4 chunks of 16B; swizzle chunk ^= (row&7)>>1 (R7-proven,
  // measured 0 conflicts). 256 threads cover 64 rows per issue; 4 issues/matrix.
  const int srow = tid >> 2;                // 0..63
  const int sc_g = ((tid & 3) ^ ((srow & 7) >> 1)) * 8;   // logical chunk elems
  const unsigned short* gA = A  + (tileM + srow) * (long long)IN_DIM + sc_g;
  const unsigned short* gB = Bw + (tileN + srow) * (long long)IN_DIM + sc_g;

  // ---- ds_read geometry (same swizzle formula; frag rows are 16-aligned) ----
  const int sc   = (((l >> 4) ^ ((l & 7) >> 1)) << 3);    // elem offset in row
  const int rbaA = (wr * 128 + (l & 15)) * BK2;
  const int rbaB = (wc * 128 + (l & 15)) * BK2;

  f32x4 acc[8][8] = {};

  // ---- prologue: stage tile 0 into buf0, drain, barrier ----
#pragma unroll
  for (int j = 0; j < 4; ++j) {
    gload16(gA + j * 64LL * IN_DIM, &lds[0][0][j * 2048 + tid * 8]);
    gload16(gB + j * 64LL * IN_DIM, &lds[0][1][j * 2048 + tid * 8]);
  }
  asm volatile("s_waitcnt vmcnt(0)" ::: "memory");
  asm volatile("s_barrier" ::: "memory");

  int buf = 0;
  for (int t = 0; t < NT2; ++t) {
    const bool more = (t + 1 < NT2);
    const unsigned short* lA = &lds[buf][0][0];
    const unsigned short* lB = &lds[buf][1][0];

    // --- issue next tile's staging first: full-tile latency cover ---
    if (more) {
      const long long ko = (long long)(t + 1) * BK2;
#pragma unroll
      for (int j = 0; j < 4; ++j) {
        gload16(gA + ko + j * 64LL * IN_DIM, &lds[buf ^ 1][0][j * 2048 + tid * 8]);
        gload16(gB + ko + j * 64LL * IN_DIM, &lds[buf ^ 1][1][j * 2048 + tid * 8]);
      }
    }

    // --- fragment reads (compiler interleaves lgkmcnt with MFMA) ---
    s16x8 af[8], bf[8];
#pragma unroll
    for (int m = 0; m < 8; ++m) af[m] = *(const s16x8*)&lA[rbaA + m * 16 * BK2 + sc];
#pragma unroll
    for (int n = 0; n < 8; ++n) bf[n] = *(const s16x8*)&lB[rbaB + n * 16 * BK2 + sc];

    __builtin_amdgcn_s_setprio(1);
#pragma unroll
    for (int m = 0; m < 8; ++m)
#pragma unroll
      for (int n = 0; n < 8; ++n)
        acc[m][n] = mfma_bf16(af[m], bf[n], acc[m][n]);
    __builtin_amdgcn_s_setprio(0);

    if (more) {
      asm volatile("s_waitcnt vmcnt(0)" ::: "memory");   // t+1 landed (cover = whole tile body)
      asm volatile("s_barrier" ::: "memory");            // publish buf^1, WAR-protect buf
    }
    buf ^= 1;
  }

  // ---- epilogue: D row = m*16 + (l>>4)*4 + r ; col = n*16 + (l&15) ----
  float bv[8];
#pragma unroll
  for (int n = 0; n < 8; ++n) bv[n] = bias[tileN + wc * 128 + n * 16 + (l & 15)];
#pragma unroll
  for (int m = 0; m < 8; ++m) {
    const long long rbase_c = tileM + wr * 128 + m * 16 + (l >> 4) * 4;
#pragma unroll
    for (int r = 0; r < 4; ++r) {
      float* crow = C + (size_t)(rbase_c + r) * OUT_DIM + tileN + wc * 128 + (l & 15);
#pragma unroll
      for (int n = 0; n < 8; ++n) crow[n * 16] = acc[m][n][r] + bv[n];
    }
  }
}

extern "C" void kernel_launch(void* const* d_in, const int* in_sizes, int n_in,
                              void* d_out, int out_size, void* d_ws, size_t ws_size,
                              hipStream_t stream) {
  const float* x       = (const float*)d_in[0];
  const float* W       = (const float*)d_in[1];
  const float* bias    = (const float*)d_in[2];
  const float* U_top   = (const float*)d_in[3];
  const float* S_top   = (const float*)d_in[4];
  const float* Vh_top  = (const float*)d_in[5];
  const float* U_tail  = (const float*)d_in[6];
  const float* S_tail  = (const float*)d_in[7];
  const float* Vh_tail = (const float*)d_in[8];
  const float* alpha   = (const float*)d_in[9];
  const float* beta    = (const float*)d_in[10];
  const float* Rm      = (const float*)d_in[11];

  char* ws = (char*)d_ws;
  unsigned short* xb = (unsigned short*)ws;                                   // 128 MB
  unsigned short* Wb = (unsigned short*)(ws + (size_t)134217728);             // 32 MB
  float* A1 = (float*)(ws + (size_t)134217728 + 33554432);
  float* A2 = A1 + (size_t)OUT_DIM * RANK;
  float* RV = A2 + (size_t)OUT_DIM * RANK;

  prep_kernel<<<(OUT_DIM * RANK) / 256, 256, 0, stream>>>(U_top, S_top, alpha, beta,
                                                          U_tail, S_tail, A1, A2);
  rv_kernel<<<dim3(IN_DIM / 256, RANK / 8), 256, 0, stream>>>(Rm, Vh_tail, RV);
  cvt_kernel<<<2048, 256, 0, stream>>>(x, xb);
  wtilde_kernel<<<dim3(IN_DIM / 256, OUT_DIM / WT_O), 256, 0, stream>>>(W, A1, A2,
                                                                        Vh_top, RV, Wb);
  gemm_kernel<<<(M_DIM / BM) * (OUT_DIM / BN), 256, 0, stream>>>(xb, Wb, bias,
                                                                 (float*)d_out);
}

// Round 9
// 752.809 us; speedup vs baseline: 4.6638x; 4.6638x over previous
//
#include <hip/hip_runtime.h>
#include <hip/hip_bf16.h>

#define OUT_DIM 4096
#define IN_DIM  4096
#define RANK    64
#define M_DIM   16384   // B*S = 4*4096

typedef short  s16x8  __attribute__((ext_vector_type(8)));
typedef __bf16 b16x8  __attribute__((ext_vector_type(8)));
typedef float  f32x4  __attribute__((ext_vector_type(4)));
typedef float  f32x16 __attribute__((ext_vector_type(16)));

// ---- 32x32x16 MFMA wrapper: tolerate either builtin signature ----
template <typename T>
__device__ static inline auto mfma32_sel(T a, T b, f32x16 c, int)
    -> decltype(__builtin_amdgcn_mfma_f32_32x32x16_bf16(a, b, c, 0, 0, 0)) {
  return __builtin_amdgcn_mfma_f32_32x32x16_bf16(a, b, c, 0, 0, 0);
}
template <typename T>
__device__ static inline f32x16 mfma32_sel(T a, T b, f32x16 c, long) {
  return __builtin_amdgcn_mfma_f32_32x32x16_bf16(
      __builtin_bit_cast(b16x8, a), __builtin_bit_cast(b16x8, b), c, 0, 0, 0);
}
__device__ static inline f32x16 mfma32(s16x8 a, s16x8 b, f32x16 c) {
  return mfma32_sel(a, b, c, 0);
}

// ---- fp32 -> bf16 bits, round-to-nearest-even ----
__device__ static inline unsigned short f2bf(float f) {
  unsigned int u = __float_as_uint(f);
  u += 0x7fffu + ((u >> 16) & 1u);
  return (unsigned short)(u >> 16);
}

// ---- async global->LDS, 16B per lane ----
__device__ static inline void gload16(const unsigned short* g, unsigned short* l) {
  __builtin_amdgcn_global_load_lds(
      (const __attribute__((address_space(1))) void*)g,
      (__attribute__((address_space(3))) void*)l, 16, 0, 0);
}

// ============ kernel 1: RV2 = diag(S_tail) * (R @ Vh_tail)  (64 x IN) ========
__global__ void rv2_kernel(const float* __restrict__ Rm, const float* __restrict__ Vh_tail,
                           const float* __restrict__ S_tail, float* __restrict__ RV2) {
  const int i  = blockIdx.x * 256 + threadIdx.x;  // 0..IN_DIM-1
  const int r0 = blockIdx.y * 8;
  float acc[8] = {};
  for (int q = 0; q < RANK; ++q) {
    float v = Vh_tail[(size_t)q * IN_DIM + i];
#pragma unroll
    for (int rr = 0; rr < 8; ++rr)
      acc[rr] = fmaf(Rm[(r0 + rr) * RANK + q], v, acc[rr]);   // uniform -> s_load
  }
#pragma unroll
  for (int rr = 0; rr < 8; ++rr)
    RV2[(size_t)(r0 + rr) * IN_DIM + i] = acc[rr] * S_tail[r0 + rr];
}

// ============ kernel 2: x -> bf16 ============
__global__ void cvt_kernel(const float* __restrict__ x, unsigned short* __restrict__ xb) {
  const long long n8 = (long long)M_DIM * IN_DIM / 8;
  long long idx = (long long)blockIdx.x * blockDim.x + threadIdx.x;
  const long long stride = (long long)gridDim.x * blockDim.x;
  for (; idx < n8; idx += stride) {
    const f32x4* p = (const f32x4*)(x + idx * 8);
    f32x4 v0 = p[0], v1 = p[1];
    s16x8 o;
    o[0] = (short)f2bf(v0[0]); o[1] = (short)f2bf(v0[1]);
    o[2] = (short)f2bf(v0[2]); o[3] = (short)f2bf(v0[3]);
    o[4] = (short)f2bf(v1[0]); o[5] = (short)f2bf(v1[1]);
    o[6] = (short)f2bf(v1[2]); o[7] = (short)f2bf(v1[3]);
    *(s16x8*)(xb + idx * 8) = o;
  }
}

// ============ kernel 3: W_tilde (bf16, [OUT][IN] = B^T layout) ============
// acc[o] = W[o][i] + sum_r U_top[o][r]*sigma[r]*Vh_top[r][i] + U_tail[o][r]*RV2[r][i]
#define WT_O 16
__global__ void wtilde_kernel(const float* __restrict__ W,      const float* __restrict__ U_top,
                              const float* __restrict__ S_top,  const float* __restrict__ alpha,
                              const float* __restrict__ beta,   const float* __restrict__ U_tail,
                              const float* __restrict__ Vh_top, const float* __restrict__ RV2,
                              unsigned short* __restrict__ Wb) {
  const int i  = blockIdx.x * 256 + threadIdx.x;
  const int o0 = blockIdx.y * WT_O;
  float acc[WT_O];
#pragma unroll
  for (int o = 0; o < WT_O; ++o) acc[o] = W[(size_t)(o0 + o) * IN_DIM + i];
#pragma unroll 4
  for (int r = 0; r < RANK; ++r) {
    float sig = fmaxf(fmaf(S_top[r], alpha[r], beta[r]), 0.f);   // uniform
    float vt  = Vh_top[(size_t)r * IN_DIM + i] * sig;
    float rv  = RV2[(size_t)r * IN_DIM + i];
#pragma unroll
    for (int o = 0; o < WT_O; ++o) {
      acc[o] = fmaf(U_top[(o0 + o) * RANK + r],  vt, acc[o]);    // uniform -> s_load
      acc[o] = fmaf(U_tail[(o0 + o) * RANK + r], rv, acc[o]);
    }
  }
#pragma unroll
  for (int o = 0; o < WT_O; ++o)
    Wb[(size_t)(o0 + o) * IN_DIM + i] = f2bf(acc[o]);
}

// ============ kernel 4: 256x256 8-phase GEMM, 32x32x16 MFMA =================
// R3-proven skeleton: 8 waves (2M x 4N), BK=64, 2-buf 128 KiB LDS,
// staging q0:B0,B1 q1:B2,B3 q2:A0,A2 q3:A1,A3 of tile t+1; waits
// vmcnt(4)@q1 / vmcnt(2)@q3; 2 barriers/phase. Phase q = m-frag quadrant
// (rows q*32..q*32+31 of the wave's 128) -- identical row ranges to R3,
// so the publication ledger carries over unchanged.
#define BM 256
#define BN 256
#define BK 64
#define NT (IN_DIM / BK)   // 64

__global__ __launch_bounds__(512, 2) void gemm_kernel(
    const unsigned short* __restrict__ A,   // xb [M][K] bf16 bits
    const unsigned short* __restrict__ Bw,  // Wb [N][K] bf16 bits
    const float* __restrict__ bias,
    float* __restrict__ C) {
  __shared__ unsigned short lds[2][2][BM * BK];   // 128 KiB

  const int tid = threadIdx.x;
  const int l   = tid & 63;
  const int wid = tid >> 6;
  const int wr  = wid >> 2;                 // 0..1  (M split)
  const int wc  = wid & 3;                  // 0..3  (N split)

  // XCD swizzle: 1024 blocks, 8 XCDs, nwg%8==0 -> simple bijection.
  const int bid = blockIdx.x;
  const int swz = (bid & 7) * 128 + (bid >> 3);
  const int nt_ = swz >> 6;                 // 0..15
  const int mt_ = swz & 63;                 // 0..63
  const long long tileM = (long long)mt_ * BM;
  const long long tileN = (long long)nt_ * BN;

  // ---- staging geometry (linear LDS dest, inverse-swizzled global src) ----
  const int rbase = tid >> 3;
  const int c8    = (((tid & 7) ^ (rbase & 7)) << 3);
  const unsigned short* gA = A  + (tileM + rbase) * (long long)IN_DIM + c8;
  const unsigned short* gB = Bw + (tileN + rbase) * (long long)IN_DIM + c8;

  // ---- ds_read geometry (32x32 frags) ----
  // A: row = wr*128 + q*32 + (l&31), k = kk*16 + (l>>5)*8 + j
  // chunk16 = kk*2 + (l>>5); phys = chunk ^ (row&7) = chunk ^ (l&7)
  const int l31 = l & 31;
  int sck[4];
#pragma unroll
  for (int kk = 0; kk < 4; ++kk)
    sck[kk] = (((kk * 2 + (l >> 5)) ^ (l & 7)) << 3);
  const int rbaA = (wr * 128 + l31) * BK;
  const int rbaB = (wc * 64  + l31) * BK;

  f32x16 acc[4][2] = {};

  // ---- prologue: stage tile 0 fully, drain, barrier ----
  {
    unsigned short* la = &lds[0][0][tid * 8];
    unsigned short* lb = &lds[0][1][tid * 8];
#pragma unroll
    for (int j = 0; j < 4; ++j) {
      gload16(gB + (long long)j * 64 * IN_DIM, lb + j * 4096);
      gload16(gA + (long long)j * 64 * IN_DIM, la + j * 4096);
    }
    asm volatile("s_waitcnt vmcnt(0)" ::: "memory");
    asm volatile("s_barrier" ::: "memory");
  }

  int buf = 0;
  for (int t = 0; t < NT; ++t) {
    const long long ktn = (long long)(t + 1) * BK;
    const bool more = (t + 1 < NT);
    const unsigned short* lA = lds[buf][0];
    const unsigned short* lB = lds[buf][1];
    unsigned short* la1 = &lds[buf ^ 1][0][tid * 8];
    unsigned short* lb1 = &lds[buf ^ 1][1][tid * 8];

    s16x8 bfr[2][4];
#pragma unroll
    for (int q = 0; q < 4; ++q) {
      // --- ds reads for this phase ---
      if (q == 0) {
#pragma unroll
        for (int n = 0; n < 2; ++n)
#pragma unroll
          for (int kk = 0; kk < 4; ++kk)
            bfr[n][kk] = *(const s16x8*)&lB[rbaB + n * 32 * BK + sck[kk]];
      }
      s16x8 afr[4];
#pragma unroll
      for (int kk = 0; kk < 4; ++kk)
        afr[kk] = *(const s16x8*)&lA[rbaA + q * 32 * BK + sck[kk]];

      // --- stage item q of tile t+1 into buf^1 (R3 order) ---
      if (more) {
        if (q == 0) {
          gload16(gB + ktn, lb1);
          gload16(gB + ktn + 1LL * 64 * IN_DIM, lb1 + 4096);
        } else if (q == 1) {
          gload16(gB + ktn + 2LL * 64 * IN_DIM, lb1 + 2 * 4096);
          gload16(gB + ktn + 3LL * 64 * IN_DIM, lb1 + 3 * 4096);
        } else if (q == 2) {
          gload16(gA + ktn, la1);
          gload16(gA + ktn + 2LL * 64 * IN_DIM, la1 + 2 * 4096);
        } else {
          gload16(gA + ktn + 1LL * 64 * IN_DIM, la1 + 1 * 4096);
          gload16(gA + ktn + 3LL * 64 * IN_DIM, la1 + 3 * 4096);
        }
      }

      asm volatile("s_barrier" ::: "memory");

      __builtin_amdgcn_s_setprio(1);
#pragma unroll
      for (int kk = 0; kk < 4; ++kk)
#pragma unroll
        for (int n = 0; n < 2; ++n)
          acc[q][n] = mfma32(afr[kk], bfr[n][kk], acc[q][n]);
      __builtin_amdgcn_s_setprio(0);

      // --- R3-proven ledger ---
      if (q == 1) {
        if (more) asm volatile("s_waitcnt vmcnt(4)" ::: "memory");
        else      asm volatile("s_waitcnt vmcnt(0)" ::: "memory");
      }
      if (q == 3 && more) {
        asm volatile("s_waitcnt vmcnt(2)" ::: "memory");
      }
      asm volatile("s_barrier" ::: "memory");
    }
    buf ^= 1;
  }

  // ---- epilogue: D col = l&31, row = (r&3) + 8*(r>>2) + 4*(l>>5)  [m74/m101] ----
  float bv[2];
#pragma unroll
  for (int n = 0; n < 2; ++n) bv[n] = bias[tileN + wc * 64 + n * 32 + l31];
#pragma unroll
  for (int m = 0; m < 4; ++m) {
    const long long rowm = tileM + wr * 128 + m * 32 + 4 * (l >> 5);
#pragma unroll
    for (int r = 0; r < 16; ++r) {
      const long long row = rowm + (r & 3) + 8 * (r >> 2);
      float* crow = C + (size_t)row * OUT_DIM + tileN + wc * 64 + l31;
#pragma unroll
      for (int n = 0; n < 2; ++n) crow[n * 32] = acc[m][n][r] + bv[n];
    }
  }
}

extern "C" void kernel_launch(void* const* d_in, const int* in_sizes, int n_in,
                              void* d_out, int out_size, void* d_ws, size_t ws_size,
                              hipStream_t stream) {
  const float* x       = (const float*)d_in[0];
  const float* W       = (const float*)d_in[1];
  const float* bias    = (const float*)d_in[2];
  const float* U_top   = (const float*)d_in[3];
  const float* S_top   = (const float*)d_in[4];
  const float* Vh_top  = (const float*)d_in[5];
  const float* U_tail  = (const float*)d_in[6];
  const float* S_tail  = (const float*)d_in[7];
  const float* Vh_tail = (const float*)d_in[8];
  const float* alpha   = (const float*)d_in[9];
  const float* beta    = (const float*)d_in[10];
  const float* Rm      = (const float*)d_in[11];

  char* ws = (char*)d_ws;
  unsigned short* xb  = (unsigned short*)ws;                                  // 128 MB
  unsigned short* Wb  = (unsigned short*)(ws + (size_t)134217728);            // 32 MB
  float*          RV2 = (float*)(ws + (size_t)134217728 + 33554432);          // 1 MB

  rv2_kernel<<<dim3(IN_DIM / 256, RANK / 8), 256, 0, stream>>>(Rm, Vh_tail, S_tail, RV2);
  cvt_kernel<<<2048, 256, 0, stream>>>(x, xb);
  wtilde_kernel<<<dim3(IN_DIM / 256, OUT_DIM / WT_O), 256, 0, stream>>>(
      W, U_top, S_top, alpha, beta, U_tail, Vh_top, RV2, Wb);
  gemm_kernel<<<(M_DIM / BM) * (OUT_DIM / BN), 512, 0, stream>>>(xb, Wb, bias,
                                                                 (float*)d_out);
}

// Round 10
// 702.772 us; speedup vs baseline: 4.9958x; 1.0712x over previous
//
#include <hip/hip_runtime.h>
#include <hip/hip_bf16.h>

#define OUT_DIM 4096
#define IN_DIM  4096
#define RANK    64
#define M_DIM   16384   // B*S = 4*4096

typedef short  s16x8 __attribute__((ext_vector_type(8)));
typedef __bf16 b16x8 __attribute__((ext_vector_type(8)));
typedef float  f32x4 __attribute__((ext_vector_type(4)));

// ---- MFMA wrapper: tolerate either builtin signature (short8 or bf16x8) ----
template <typename T>
__device__ static inline auto mfma_sel(T a, T b, f32x4 c, int)
    -> decltype(__builtin_amdgcn_mfma_f32_16x16x32_bf16(a, b, c, 0, 0, 0)) {
  return __builtin_amdgcn_mfma_f32_16x16x32_bf16(a, b, c, 0, 0, 0);
}
template <typename T>
__device__ static inline f32x4 mfma_sel(T a, T b, f32x4 c, long) {
  return __builtin_amdgcn_mfma_f32_16x16x32_bf16(
      __builtin_bit_cast(b16x8, a), __builtin_bit_cast(b16x8, b), c, 0, 0, 0);
}
__device__ static inline f32x4 mfma_bf16(s16x8 a, s16x8 b, f32x4 c) {
  return mfma_sel(a, b, c, 0);
}

// ---- fp32 -> bf16 bits, round-to-nearest-even ----
__device__ static inline unsigned short f2bf(float f) {
  unsigned int u = __float_as_uint(f);
  u += 0x7fffu + ((u >> 16) & 1u);
  return (unsigned short)(u >> 16);
}

// ---- async global->LDS, 16B per lane ----
__device__ static inline void gload16(const unsigned short* g, unsigned short* l) {
  __builtin_amdgcn_global_load_lds(
      (const __attribute__((address_space(1))) void*)g,
      (__attribute__((address_space(3))) void*)l, 16, 0, 0);
}

// ============ kernel 1: RV2 = diag(S_tail) * (R @ Vh_tail)  (64 x IN) ========
__global__ void rv2_kernel(const float* __restrict__ Rm, const float* __restrict__ Vh_tail,
                           const float* __restrict__ S_tail, float* __restrict__ RV2) {
  const int i  = blockIdx.x * 256 + threadIdx.x;  // 0..IN_DIM-1
  const int r0 = blockIdx.y * 8;
  float acc[8] = {};
  for (int q = 0; q < RANK; ++q) {
    float v = Vh_tail[(size_t)q * IN_DIM + i];
#pragma unroll
    for (int rr = 0; rr < 8; ++rr)
      acc[rr] = fmaf(Rm[(r0 + rr) * RANK + q], v, acc[rr]);   // uniform -> s_load
  }
#pragma unroll
  for (int rr = 0; rr < 8; ++rr)
    RV2[(size_t)(r0 + rr) * IN_DIM + i] = acc[rr] * S_tail[r0 + rr];
}

// ============ kernel 2: FUSED  cvt (x->bf16)  +  W_tilde build ==============
// blocks [0, CVT_BLOCKS)            : grid-stride x -> xb conversion
// blocks [CVT_BLOCKS, +WT_BLOCKS)   : W_tilde (bf16, [OUT][IN] = B^T layout)
// No data dependency between the two halves; fusing overlaps HBM (cvt) with
// VALU+HBM (wtilde) across CUs and saves one launch.
#define CVT_BLOCKS 2048
#define WT_O 16
#define WT_BLOCKS ((IN_DIM / 256) * (OUT_DIM / WT_O))   // 16*256 = 4096
__global__ void prep_fused_kernel(const float* __restrict__ x, unsigned short* __restrict__ xb,
                                  const float* __restrict__ W,      const float* __restrict__ U_top,
                                  const float* __restrict__ S_top,  const float* __restrict__ alpha,
                                  const float* __restrict__ beta,   const float* __restrict__ U_tail,
                                  const float* __restrict__ Vh_top, const float* __restrict__ RV2,
                                  unsigned short* __restrict__ Wb) {
  const int tid = threadIdx.x;
  if (blockIdx.x < CVT_BLOCKS) {
    // ---- cvt half ----
    const long long n8 = (long long)M_DIM * IN_DIM / 8;
    long long idx = (long long)blockIdx.x * 256 + tid;
    const long long stride = (long long)CVT_BLOCKS * 256;
    for (; idx < n8; idx += stride) {
      const f32x4* p = (const f32x4*)(x + idx * 8);
      f32x4 v0 = p[0], v1 = p[1];
      s16x8 o;
      o[0] = (short)f2bf(v0[0]); o[1] = (short)f2bf(v0[1]);
      o[2] = (short)f2bf(v0[2]); o[3] = (short)f2bf(v0[3]);
      o[4] = (short)f2bf(v1[0]); o[5] = (short)f2bf(v1[1]);
      o[6] = (short)f2bf(v1[2]); o[7] = (short)f2bf(v1[3]);
      *(s16x8*)(xb + idx * 8) = o;
    }
  } else {
    // ---- wtilde half ----
    const int rem = blockIdx.x - CVT_BLOCKS;
    const int i   = (rem & 15) * 256 + tid;      // 0..IN_DIM-1
    const int o0  = (rem >> 4) * WT_O;           // 0..OUT_DIM-16
    float acc[WT_O];
#pragma unroll
    for (int o = 0; o < WT_O; ++o) acc[o] = W[(size_t)(o0 + o) * IN_DIM + i];
#pragma unroll 4
    for (int r = 0; r < RANK; ++r) {
      float sig = fmaxf(fmaf(S_top[r], alpha[r], beta[r]), 0.f);   // uniform
      float vt  = Vh_top[(size_t)r * IN_DIM + i] * sig;
      float rv  = RV2[(size_t)r * IN_DIM + i];
#pragma unroll
      for (int o = 0; o < WT_O; ++o) {
        acc[o] = fmaf(U_top[(o0 + o) * RANK + r],  vt, acc[o]);    // uniform -> s_load
        acc[o] = fmaf(U_tail[(o0 + o) * RANK + r], rv, acc[o]);
      }
    }
#pragma unroll
    for (int o = 0; o < WT_O; ++o)
      Wb[(size_t)(o0 + o) * IN_DIM + i] = f2bf(acc[o]);
  }
}

// ============ kernel 3: 256x256 8-phase GEMM (R3-exact, proven 500us) =======
// 8 waves (2M x 4N), BK=64, 2-buf 128 KiB LDS, counted vmcnt,
// chunk-XOR LDS swizzle (c ^= row&7), XCD-aware block swizzle.
#define BM 256
#define BN 256
#define BK 64
#define NT (IN_DIM / BK)   // 64

__global__ __launch_bounds__(512, 2) void gemm_kernel(
    const unsigned short* __restrict__ A,   // xb [M][K] bf16 bits
    const unsigned short* __restrict__ Bw,  // Wb [N][K] bf16 bits
    const float* __restrict__ bias,
    float* __restrict__ C) {
  // [buf][mat(0=A,1=B)][256*64 elems]  = 128 KiB
  __shared__ unsigned short lds[2][2][BM * BK];

  const int tid = threadIdx.x;
  const int l   = tid & 63;
  const int wid = tid >> 6;
  const int wr  = wid >> 2;                 // 0..1  (M split)
  const int wc  = wid & 3;                  // 0..3  (N split)

  // XCD swizzle: 1024 blocks, 8 XCDs, nwg%8==0 -> simple bijection.
  const int bid = blockIdx.x;
  const int swz = (bid & 7) * 128 + (bid >> 3);
  const int nt_ = swz >> 6;                 // 0..15
  const int mt_ = swz & 63;                 // 0..63
  const long long tileM = (long long)mt_ * BM;
  const long long tileN = (long long)nt_ * BN;

  // ---- staging geometry (linear LDS dest, inverse-swizzled global src) ----
  const int rbase = tid >> 3;
  const int c8    = (((tid & 7) ^ (rbase & 7)) << 3);
  const unsigned short* gA = A  + (tileM + rbase) * (long long)IN_DIM + c8;
  const unsigned short* gB = Bw + (tileN + rbase) * (long long)IN_DIM + c8;

  // ---- ds_read geometry ----
  const int kgrp = l >> 4;                  // 0..3
  const int x7   = l & 7;
  const int sc0  = (((0 * 4 + kgrp) ^ x7) << 3);
  const int sc1  = (((1 * 4 + kgrp) ^ x7) << 3);
  const int rba  = (wr * 128 + (l & 15)) * BK;
  const int rbb  = (wc * 64  + (l & 15)) * BK;

  f32x4 acc[8][4] = {};

  // ---- prologue: stage tile 0 fully, drain, barrier ----
  {
    unsigned short* la = &lds[0][0][tid * 8];
    unsigned short* lb = &lds[0][1][tid * 8];
#pragma unroll
    for (int j = 0; j < 4; ++j) {
      gload16(gB + (long long)j * 64 * IN_DIM, lb + j * 4096);
      gload16(gA + (long long)j * 64 * IN_DIM, la + j * 4096);
    }
    asm volatile("s_waitcnt vmcnt(0)" ::: "memory");
    asm volatile("s_barrier" ::: "memory");
  }

  int buf = 0;
  for (int t = 0; t < NT; ++t) {
    const long long ktn = (long long)(t + 1) * BK;
    const bool more = (t + 1 < NT);
    const unsigned short* lA = lds[buf][0];
    const unsigned short* lB = lds[buf][1];
    unsigned short* la1 = &lds[buf ^ 1][0][tid * 8];
    unsigned short* lb1 = &lds[buf ^ 1][1][tid * 8];

    s16x8 bfr[4][2];
#pragma unroll
    for (int q = 0; q < 4; ++q) {
      // --- ds reads for this phase (from buf) ---
      if (q == 0) {
#pragma unroll
        for (int n = 0; n < 4; ++n) {
          bfr[n][0] = *(const s16x8*)&lB[rbb + n * 16 * BK + sc0];
          bfr[n][1] = *(const s16x8*)&lB[rbb + n * 16 * BK + sc1];
        }
      }
      s16x8 afr[2][2];
#pragma unroll
      for (int m2 = 0; m2 < 2; ++m2) {
        afr[m2][0] = *(const s16x8*)&lA[rba + (q * 32 + m2 * 16) * BK + sc0];
        afr[m2][1] = *(const s16x8*)&lA[rba + (q * 32 + m2 * 16) * BK + sc1];
      }

      // --- stage item q of tile t+1 into buf^1 ---
      if (more) {
        if (q == 0) {
          gload16(gB + ktn, lb1);
          gload16(gB + ktn + 1LL * 64 * IN_DIM, lb1 + 4096);
        } else if (q == 1) {
          gload16(gB + ktn + 2LL * 64 * IN_DIM, lb1 + 2 * 4096);
          gload16(gB + ktn + 3LL * 64 * IN_DIM, lb1 + 3 * 4096);
        } else if (q == 2) {
          gload16(gA + ktn, la1);
          gload16(gA + ktn + 2LL * 64 * IN_DIM, la1 + 2 * 4096);
        } else {
          gload16(gA + ktn + 1LL * 64 * IN_DIM, la1 + 1 * 4096);
          gload16(gA + ktn + 3LL * 64 * IN_DIM, la1 + 3 * 4096);
        }
      }

      asm volatile("s_barrier" ::: "memory");

      __builtin_amdgcn_s_setprio(1);
#pragma unroll
      for (int m2 = 0; m2 < 2; ++m2)
#pragma unroll
        for (int n = 0; n < 4; ++n)
#pragma unroll
          for (int kk = 0; kk < 2; ++kk)
            acc[q * 2 + m2][n] = mfma_bf16(afr[m2][kk], bfr[n][kk], acc[q * 2 + m2][n]);
      __builtin_amdgcn_s_setprio(0);

      // --- phase-closing waits (counted, never 0 in steady state) ---
      if (q == 1) {
        if (more) asm volatile("s_waitcnt vmcnt(4)" ::: "memory");
        else      asm volatile("s_waitcnt vmcnt(0)" ::: "memory");
      }
      if (q == 3 && more) {
        asm volatile("s_waitcnt vmcnt(2)" ::: "memory");
      }
      asm volatile("s_barrier" ::: "memory");
    }
    buf ^= 1;
  }

  // ---- epilogue: D row = m*16 + (l>>4)*4 + r ; col = n*16 + (l&15) ----
  float bv[4];
#pragma unroll
  for (int n = 0; n < 4; ++n) bv[n] = bias[tileN + wc * 64 + n * 16 + (l & 15)];
#pragma unroll
  for (int m = 0; m < 8; ++m) {
    const long long rbase_c = tileM + wr * 128 + m * 16 + (l >> 4) * 4;
#pragma unroll
    for (int r = 0; r < 4; ++r) {
      float* crow = C + (size_t)(rbase_c + r) * OUT_DIM + tileN + wc * 64 + (l & 15);
#pragma unroll
      for (int n = 0; n < 4; ++n) crow[n * 16] = acc[m][n][r] + bv[n];
    }
  }
}

extern "C" void kernel_launch(void* const* d_in, const int* in_sizes, int n_in,
                              void* d_out, int out_size, void* d_ws, size_t ws_size,
                              hipStream_t stream) {
  const float* x       = (const float*)d_in[0];
  const float* W       = (const float*)d_in[1];
  const float* bias    = (const float*)d_in[2];
  const float* U_top   = (const float*)d_in[3];
  const float* S_top   = (const float*)d_in[4];
  const float* Vh_top  = (const float*)d_in[5];
  const float* U_tail  = (const float*)d_in[6];
  const float* S_tail  = (const float*)d_in[7];
  const float* Vh_tail = (const float*)d_in[8];
  const float* alpha   = (const float*)d_in[9];
  const float* beta    = (const float*)d_in[10];
  const float* Rm      = (const float*)d_in[11];

  char* ws = (char*)d_ws;
  unsigned short* xb  = (unsigned short*)ws;                                  // 128 MB
  unsigned short* Wb  = (unsigned short*)(ws + (size_t)134217728);            // 32 MB
  float*          RV2 = (float*)(ws + (size_t)134217728 + 33554432);          // 1 MB

  rv2_kernel<<<dim3(IN_DIM / 256, RANK / 8), 256, 0, stream>>>(Rm, Vh_tail, S_tail, RV2);
  prep_fused_kernel<<<CVT_BLOCKS + WT_BLOCKS, 256, 0, stream>>>(
      x, xb, W, U_top, S_top, alpha, beta, U_tail, Vh_top, RV2, Wb);
  gemm_kernel<<<(M_DIM / BM) * (OUT_DIM / BN), 512, 0, stream>>>(xb, Wb, bias,
                                                                 (float*)d_out);
}